// Round 1
// 320.428 us; speedup vs baseline: 1.0773x; 1.0773x over previous
//
#include <hip/hip_runtime.h>

typedef __attribute__((ext_vector_type(8))) short bf16x8;
typedef __attribute__((ext_vector_type(4))) float floatx4;

constexpr int BATCH = 4;
constexpr int SEQ   = 2048;
constexpr int DIMN  = 1024;
constexpr int M1    = BATCH * SEQ; // 8192

__device__ __forceinline__ short f2bf(float f) {
    union { float f; unsigned u; } x; x.f = f;
    unsigned r = x.u + 0x7fffu + ((x.u >> 16) & 1u); // RNE
    return (short)(r >> 16);
}
__device__ __forceinline__ float bf2f(short s) {
    union { unsigned u; float f; } x; x.u = ((unsigned)(unsigned short)s) << 16;
    return x.f;
}

__device__ __forceinline__ void async16(const void* g, void* l) {
    __builtin_amdgcn_global_load_lds(
        (const __attribute__((address_space(1))) unsigned int*)g,
        (__attribute__((address_space(3))) unsigned int*)l, 16, 0, 0);
}

#define WAITVM(N) asm volatile("s_waitcnt vmcnt(" #N ")" ::: "memory")
#define MEMFENCE  asm volatile("" ::: "memory")

// ---------------------------------------------------------------------------
// Deep-pipelined GEMM core: C = A @ B^T (*scale + bias), bf16 in.
// Tile 256(M) x 128(N) x 64(K); 8 waves (2M x 4N), per-wave 128x32 output.
// LDS: 3 buffers x (A 32KB + B 16KB) = 144 KB, 128-B rows with involution
// swizzle  byte ^= ((row&7)<<4)  (T2): applied on the PRE-SWIZZLED global
// source (global_load_lds writes linearly) and on the ds_read address.
// Pipeline: loads for tile t+2 issued during tile t (3+3 per phase);
// counted vmcnt(9) once per K-tile (T4), setprio around MFMA (T5).
// ---------------------------------------------------------------------------
template<bool OUT_BF16>
__device__ __forceinline__ void gemm256(
    const short* __restrict__ Ab, int lda,
    const short* __restrict__ Bb, int ldb,
    void* __restrict__ Cb, int ldc,
    const float* __restrict__ bias, int K, float scale,
    int m0, int n0)
{
    __shared__ alignas(16) char smem[3][49152];   // per buf: A [256][64] @0, B [128][64] @32768

    const int t    = threadIdx.x;      // 0..511
    const int lane = t & 63;
    const int wave = t >> 6;
    const int wr   = wave >> 2;        // 0..1  (M half)
    const int wc   = wave & 3;         // 0..3  (N quarter)
    const int lr   = lane & 15;
    const int lq   = lane >> 4;

    // ---- staging source pointers: physical LDS byte P (linear, t*16 within
    // each 8KB set) holds global data of logical byte L = P ^ ((P>>7 & 7)<<4).
    const short* pA[4];
    const short* pB[2];
    #pragma unroll
    for (int s = 0; s < 4; ++s) {
        const int P = s * 8192 + t * 16;
        const int L = P ^ (((P >> 7) & 7) << 4);
        pA[s] = Ab + (size_t)(m0 + (L >> 7)) * lda + ((L & 127) >> 1);
    }
    #pragma unroll
    for (int s = 0; s < 2; ++s) {
        const int P = s * 8192 + t * 16;
        const int L = P ^ (((P >> 7) & 7) << 4);
        pB[s] = Bb + (size_t)(n0 + (L >> 7)) * ldb + ((L & 127) >> 1);
    }

    // ---- swizzled read offsets (row&7 == lane&7 for all fragment rows)
    int roA[8], roB[2], colp[2];
    #pragma unroll
    for (int m = 0; m < 8; ++m) roA[m] = (wr * 128 + m * 16 + lr) * 128;
    #pragma unroll
    for (int n = 0; n < 2; ++n) roB[n] = 32768 + (wc * 32 + n * 16 + lr) * 128;
    #pragma unroll
    for (int kk = 0; kk < 2; ++kk)
        colp[kk] = ((kk << 6) | (lq << 4)) ^ ((lane & 7) << 4);

    floatx4 acc[8][2];
    #pragma unroll
    for (int m = 0; m < 8; ++m)
        #pragma unroll
        for (int n = 0; n < 2; ++n) acc[m][n] = (floatx4)(0.f);

    const int ldst = t * 16;
    auto stage_a = [&](int sb) {              // A sets 0..2 (3 loads)
        char* base = smem[sb];
        async16(pA[0], base +          ldst);
        async16(pA[1], base +  8192 + ldst);
        async16(pA[2], base + 16384 + ldst);
        pA[0] += 64; pA[1] += 64; pA[2] += 64;
    };
    auto stage_b = [&](int sb) {              // A set 3 + B sets 0..1 (3 loads)
        char* base = smem[sb];
        async16(pA[3], base + 24576 + ldst);
        async16(pB[0], base + 32768 + ldst);
        async16(pB[1], base + 40960 + ldst);
        pA[3] += 64; pB[0] += 64; pB[1] += 64;
    };
    auto compute = [&](int buf, int kk) {
        const char* base = smem[buf];
        bf16x8 a[8], bfr[2];
        #pragma unroll
        for (int m = 0; m < 8; ++m)
            a[m] = *(const bf16x8*)(base + roA[m] + colp[kk]);
        #pragma unroll
        for (int n = 0; n < 2; ++n)
            bfr[n] = *(const bf16x8*)(base + roB[n] + colp[kk]);
        __builtin_amdgcn_s_setprio(1);
        #pragma unroll
        for (int m = 0; m < 8; ++m)
            #pragma unroll
            for (int n = 0; n < 2; ++n)
                acc[m][n] = __builtin_amdgcn_mfma_f32_16x16x32_bf16(
                    a[m], bfr[n], acc[m][n], 0, 0, 0);
        __builtin_amdgcn_s_setprio(0);
    };

    const int NT = K >> 6;
    // prologue: tiles 0 and 1 fully staged
    stage_a(0); stage_b(0);
    stage_a(1); stage_b(1);

    int buf = 0;
    for (int tt = 0; tt < NT; ++tt) {
        const int  sb  = (buf == 0) ? 2 : buf - 1;   // (tt+2)%3
        const bool stg = (tt + 2) < NT;
        // -------- phase 0 (kk=0): stage A of tile t+2, certify tile t ------
        if (stg) stage_a(sb);
        if (tt + 2 < NT)      { WAITVM(9); }   // 9 = loads newer than tile t
        else if (tt + 1 < NT) { WAITVM(6); }
        else                  { WAITVM(0); }
        __builtin_amdgcn_s_barrier();          // all waves passed their vmcnt
        MEMFENCE;
        compute(buf, 0);
        MEMFENCE;
        __builtin_amdgcn_s_barrier();          // buffer-reuse certification
        // -------- phase 1 (kk=1): stage B of tile t+2 ----------------------
        if (stg) stage_b(sb);
        __builtin_amdgcn_s_barrier();
        MEMFENCE;
        compute(buf, 1);
        MEMFENCE;
        __builtin_amdgcn_s_barrier();
        buf = (buf == 2) ? 0 : buf + 1;
    }

    // ---- epilogue. D layout: col = lane&15, row = (lane>>4)*4 + r ---------
    #pragma unroll
    for (int n = 0; n < 2; ++n) {
        const int gn = n0 + wc * 32 + n * 16 + lr;
        const float bv = bias ? bias[gn] : 0.f;
        #pragma unroll
        for (int m = 0; m < 8; ++m) {
            #pragma unroll
            for (int r = 0; r < 4; ++r) {
                const int gm = m0 + wr * 128 + m * 16 + lq * 4 + r;
                const float v = acc[m][n][r] * scale + bv;
                if (OUT_BF16) ((short*)Cb)[(size_t)gm * ldc + gn] = f2bf(v);
                else          ((float*)Cb)[(size_t)gm * ldc + gn] = v;
            }
        }
    }
}

// ---------------------------------------------------------------------------
// Projections: 768 blocks = 3 mats x 32 m-tiles x 8 n-tiles, XCD-swizzled
// (each XCD owns 4 contiguous m-tiles; z slowest so phases stream per-XCD).
// ---------------------------------------------------------------------------
__global__ __launch_bounds__(512)
void proj_qkv(const short* __restrict__ xq, const short* __restrict__ xk,
              const short* __restrict__ xv,
              const short* __restrict__ Wq_, const short* __restrict__ Wk_,
              const short* __restrict__ Wv_,
              const float* __restrict__ bq_, const float* __restrict__ bk_,
              const float* __restrict__ bv_,
              short* __restrict__ q, short* __restrict__ k, short* __restrict__ vp)
{
    const int b   = blockIdx.x;
    const int xcd = b & 7;
    const int i   = b >> 3;          // 0..95
    const int z   = i >> 5;          // 0..2 (q,k,v)
    const int r   = i & 31;
    const int mm  = r >> 3;          // 0..3
    const int nn  = r & 7;           // 0..7
    const short* X = (z == 0) ? xq : (z == 1) ? xk : xv;
    const short* W = (z == 0) ? Wq_ : (z == 1) ? Wk_ : Wv_;
    const float* bb = (z == 0) ? bq_ : (z == 1) ? bk_ : bv_;
    short* O = (z == 0) ? q : (z == 1) ? k : vp;
    gemm256<true>(X, DIMN, W, DIMN, (void*)O, DIMN, bb, DIMN, 1.f,
                  (xcd * 4 + mm) * 256, nn * 128);
}

// scores: 512 blocks. batch = xcd>>1 (2 XCDs per batch), m-half = xcd&1.
__global__ __launch_bounds__(512)
void gemm_scores(const short* __restrict__ q, const short* __restrict__ k,
                 short* __restrict__ S, float scale)
{
    const int b   = blockIdx.x;
    const int xcd = b & 7;
    const int i   = b >> 3;          // 0..63
    const int bz  = xcd >> 1;
    const int mh  = xcd & 1;
    const int mm  = i >> 4;          // 0..3
    const int nn  = i & 15;          // 0..15
    gemm256<true>(q + (size_t)bz * SEQ * DIMN, DIMN,
                  k + (size_t)bz * SEQ * DIMN, DIMN,
                  (void*)(S + (size_t)bz * SEQ * SEQ), SEQ,
                  nullptr, DIMN, scale,
                  (mh * 4 + mm) * 256, nn * 128);
}

// PV: 256 blocks (exactly one scheduling round), K = 2048.
__global__ __launch_bounds__(512)
void gemm_pv(const short* __restrict__ P, const short* __restrict__ vt,
             float* __restrict__ O)
{
    const int b   = blockIdx.x;
    const int xcd = b & 7;
    const int i   = b >> 3;          // 0..31
    const int bz  = xcd >> 1;
    const int mh  = xcd & 1;
    const int mm  = i >> 3;          // 0..3
    const int nn  = i & 7;           // 0..7
    gemm256<false>(P  + (size_t)bz * SEQ * SEQ,  SEQ,
                   vt + (size_t)bz * DIMN * SEQ, SEQ,
                   (void*)(O + (size_t)bz * SEQ * DIMN), DIMN,
                   nullptr, SEQ, 1.f,
                   (mh * 4 + mm) * 256, nn * 128);
}

// ---------------------------------------------------------------------------
// fp32 -> bf16 bulk convert, up to 3 arrays per launch (blockIdx.z picks).
// ---------------------------------------------------------------------------
__global__ __launch_bounds__(256)
void cvt_tri(const float* __restrict__ in0, short* __restrict__ out0,
             const float* __restrict__ in1, short* __restrict__ out1,
             const float* __restrict__ in2, short* __restrict__ out2, int n8)
{
    const int z = blockIdx.z;
    const float* in = (z == 0) ? in0 : (z == 1) ? in1 : in2;
    short* out      = (z == 0) ? out0 : (z == 1) ? out1 : out2;
    const int i = blockIdx.x * 256 + threadIdx.x;
    if (i >= n8) return;
    const float4 a0 = ((const float4*)in)[(size_t)i * 2];
    const float4 a1 = ((const float4*)in)[(size_t)i * 2 + 1];
    const float v[8] = {a0.x, a0.y, a0.z, a0.w, a1.x, a1.y, a1.z, a1.w};
    bf16x8 o;
    #pragma unroll
    for (int j = 0; j < 8; ++j) o[j] = f2bf(v[j]);
    *(bf16x8*)(out + (size_t)i * 8) = o;
}

// ---------------------------------------------------------------------------
// Effective biases: out[n] = b[n] + dot(ctx, W[n,:]) (ctx only for q,k).
// ---------------------------------------------------------------------------
__global__ __launch_bounds__(256)
void bias3(const float* __restrict__ Wq, const float* __restrict__ Wk,
           const float* __restrict__ Wv,
           const float* __restrict__ bq, const float* __restrict__ bk,
           const float* __restrict__ bv,
           const float* __restrict__ ctx,
           float* __restrict__ oq, float* __restrict__ ok, float* __restrict__ ov)
{
    const int z = blockIdx.y;
    const float* W = (z == 0) ? Wq : (z == 1) ? Wk : Wv;
    const float* b = (z == 0) ? bq : (z == 1) ? bk : bv;
    float*       o = (z == 0) ? oq : (z == 1) ? ok : ov;
    const int n    = blockIdx.x * 4 + (threadIdx.x >> 6);
    const int lane = threadIdx.x & 63;
    float s = 0.f;
    if (z < 2) {
        const float* row = W + (size_t)n * DIMN;
        for (int k = lane * 4; k < DIMN; k += 256) {
            const float4 x = *(const float4*)(row + k);
            const float4 c = *(const float4*)(ctx + k);
            s += x.x * c.x + x.y * c.y + x.z * c.z + x.w * c.w;
        }
        #pragma unroll
        for (int off = 32; off > 0; off >>= 1) s += __shfl_xor(s, off);
    }
    if (lane == 0) o[n] = b[n] + s;
}

// ---------------------------------------------------------------------------
// bf16 transpose: in [B][S][D] -> out [B][D][S], 64x64 LDS tiles.
// ---------------------------------------------------------------------------
__global__ __launch_bounds__(256)
void transpose_v(const short* __restrict__ in, short* __restrict__ out)
{
    __shared__ short t[64][68];
    const int b  = blockIdx.z;
    const int d0 = blockIdx.x * 64;
    const int s0 = blockIdx.y * 64;
    const int r  = threadIdx.x >> 3;
    const int c  = (threadIdx.x & 7) * 8;
    #pragma unroll
    for (int h = 0; h < 2; ++h) {
        const int s = r + h * 32;
        bf16x8 v = *(const bf16x8*)(in + ((size_t)b * SEQ + s0 + s) * DIMN + d0 + c);
        #pragma unroll
        for (int j = 0; j < 8; ++j) t[c + j][s] = v[j];
    }
    __syncthreads();
    #pragma unroll
    for (int h = 0; h < 2; ++h) {
        const int d = r + h * 32;
        bf16x8 v;
        #pragma unroll
        for (int j = 0; j < 8; ++j) v[j] = t[d][c + j];
        *(bf16x8*)(out + ((size_t)b * DIMN + d0 + d) * SEQ + s0 + c) = v;
    }
}

// ---------------------------------------------------------------------------
// Row softmax, in place on bf16 [M1 rows][SEQ]. XCD-aligned with scores'
// writer (batch bz lives on XCDs {2bz, 2bz+1}) so reads hit that L2.
// ---------------------------------------------------------------------------
__global__ __launch_bounds__(256)
void softmax_kernel(short* __restrict__ P)
{
    const int bid = blockIdx.x;
    const int xcd = bid & 7;
    const int i   = bid >> 3;            // 0..1023
    const int row = (xcd >> 1) * SEQ + (xcd & 1) * 1024 + i;
    short* p = P + (size_t)row * SEQ;
    const int t    = threadIdx.x;
    const int lane = t & 63;
    const int wave = t >> 6;
    __shared__ float red[8];

    bf16x8 raw = *(const bf16x8*)(p + t * 8);
    float v[8];
    float mx = -1e30f;
    #pragma unroll
    for (int j = 0; j < 8; ++j) { v[j] = bf2f(raw[j]); mx = fmaxf(mx, v[j]); }
    #pragma unroll
    for (int off = 32; off > 0; off >>= 1) mx = fmaxf(mx, __shfl_xor(mx, off));
    if (lane == 0) red[wave] = mx;
    __syncthreads();
    mx = fmaxf(fmaxf(red[0], red[1]), fmaxf(red[2], red[3]));

    float e[8], s = 0.f;
    #pragma unroll
    for (int j = 0; j < 8; ++j) { e[j] = __expf(v[j] - mx); s += e[j]; }
    #pragma unroll
    for (int off = 32; off > 0; off >>= 1) s += __shfl_xor(s, off);
    if (lane == 0) red[4 + wave] = s;
    __syncthreads();
    s = red[4] + red[5] + red[6] + red[7];
    const float inv = 1.f / s;

    bf16x8 o;
    #pragma unroll
    for (int j = 0; j < 8; ++j) o[j] = f2bf(e[j] * inv);
    *(bf16x8*)(p + t * 8) = o;
}

// ---------------------------------------------------------------------------
extern "C" void kernel_launch(void* const* d_in, const int* in_sizes, int n_in,
                              void* d_out, int out_size, void* d_ws, size_t ws_size,
                              hipStream_t stream)
{
    const float* query = (const float*)d_in[0];
    const float* key_  = (const float*)d_in[1];
    const float* value = (const float*)d_in[2];
    const float* ctx   = (const float*)d_in[3];
    const float* Wq    = (const float*)d_in[4];
    const float* bq    = (const float*)d_in[5];
    const float* Wk    = (const float*)d_in[6];
    const float* bk    = (const float*)d_in[7];
    const float* Wv    = (const float*)d_in[8];
    const float* bv    = (const float*)d_in[9];

    // Workspace (80 MB) + d_out (32 MB) doubling as scratch for xv/vp:
    //   ws:  xq [0,16) xk [16,32)  -> dead after proj -> S_b [0,32)
    //        q_b [32,48) k_b [48,64)
    //        W3 [64,70) + biases    -> dead after proj -> v_t [64,80)
    //   d_out: xv [0,16) vp [16,32) -> dead after transpose -> final output
    char* ws = (char*)d_ws;
    char* od = (char*)d_out;
    const size_t MB = 1ull << 20;
    short* xq   = (short*)(ws);
    short* xk   = (short*)(ws + 16 * MB);
    short* q_b  = (short*)(ws + 32 * MB);
    short* k_b  = (short*)(ws + 48 * MB);
    short* Wq_b = (short*)(ws + 64 * MB);
    short* Wk_b = (short*)(ws + 66 * MB);
    short* Wv_b = (short*)(ws + 68 * MB);
    float* bq_e = (float*)(ws + 70 * MB);
    float* bk_e = (float*)(ws + 70 * MB + 4096);
    float* bv_e = (float*)(ws + 70 * MB + 8192);
    short* S_b  = (short*)(ws);
    short* v_t  = (short*)(ws + 64 * MB);
    short* xv   = (short*)(od);
    short* vp   = (short*)(od + 16 * MB);

    dim3 blk(256);
    dim3 blk512(512);
    const int W8 = DIMN * DIMN / 8;  // 131072
    const int X8 = M1 * DIMN / 8;    // 1048576

    cvt_tri<<<dim3(W8 / 256, 1, 3), blk, 0, stream>>>(Wq, Wq_b, Wk, Wk_b, Wv, Wv_b, W8);
    bias3<<<dim3(DIMN / 4, 3), blk, 0, stream>>>(Wq, Wk, Wv, bq, bk, bv, ctx,
                                                 bq_e, bk_e, bv_e);
    cvt_tri<<<dim3(X8 / 256, 1, 3), blk, 0, stream>>>(query, xq, key_, xk, value, xv, X8);

    proj_qkv<<<dim3(768), blk512, 0, stream>>>(xq, xk, xv, Wq_b, Wk_b, Wv_b,
                                               bq_e, bk_e, bv_e, q_b, k_b, vp);
    transpose_v<<<dim3(DIMN / 64, SEQ / 64, BATCH), blk, 0, stream>>>(vp, v_t);

    const float scale = 1.0f / 32.0f; // DIMN^-0.5
    gemm_scores<<<dim3(512), blk512, 0, stream>>>(q_b, k_b, S_b, scale);

    softmax_kernel<<<dim3(M1), blk, 0, stream>>>(S_b);

    gemm_pv<<<dim3(256), blk512, 0, stream>>>(S_b, v_t, (float*)d_out);
}

// Round 2
// 304.296 us; speedup vs baseline: 1.1344x; 1.0530x over previous
//
#include <hip/hip_runtime.h>

typedef __attribute__((ext_vector_type(8))) short bf16x8;
typedef __attribute__((ext_vector_type(4))) float floatx4;

constexpr int BATCH = 4;
constexpr int SEQ   = 2048;
constexpr int DIMN  = 1024;
constexpr int M1    = BATCH * SEQ; // 8192

__device__ __forceinline__ short f2bf(float f) {
    union { float f; unsigned u; } x; x.f = f;
    unsigned r = x.u + 0x7fffu + ((x.u >> 16) & 1u); // RNE
    return (short)(r >> 16);
}
__device__ __forceinline__ float bf2f(short s) {
    union { unsigned u; float f; } x; x.u = ((unsigned)(unsigned short)s) << 16;
    return x.f;
}

__device__ __forceinline__ void async16(const void* g, void* l) {
    __builtin_amdgcn_global_load_lds(
        (const __attribute__((address_space(1))) unsigned int*)g,
        (__attribute__((address_space(3))) unsigned int*)l, 16, 0, 0);
}

#define WAITVM(N) asm volatile("s_waitcnt vmcnt(" #N ")" ::: "memory")
#define MEMFENCE  asm volatile("" ::: "memory")
#define BAR()     __builtin_amdgcn_s_barrier()
#define PRIO(x)   __builtin_amdgcn_s_setprio(x)

// ---------------------------------------------------------------------------
// Deep-pipelined GEMM core: C = A @ B^T (*scale + bias), bf16 in.
// BN=256 fixed, 8 waves as 2(M) x 4(N); per-wave output (WM*16) x 64.
//   WM=8: 256x256 tile, 4 phases/K-tile (16 MFMA each)
//   WM=4: 128x256 tile, 2 phases/K-tile (16 MFMA each, both kk merged)
// LDS: 2 buffers x (A WM*4KB + B 32KB); 128-B rows, involution swizzle
//   byte ^= ((row&7)<<4) applied on the pre-swizzled global source (since
//   global_load_lds writes linearly) and on the ds_read address.
// Staging (race-free by barrier ordering):
//   B(t+1) -> other buffer, staged in early phases (other buf's reads were
//             certified by the previous tile's barriers);
//   A(t+2) -> current buffer, staged only AFTER the barrier certifying all
//             current-tile A-reads complete.
// One counted vmcnt(ACH) per K-tile (ACH = in-flight A(t+2) loads); newest
// needed load always has >=1 full phase (~600 cy) of slack.
// ---------------------------------------------------------------------------
template<bool OUT_BF16, int WM>
__device__ __forceinline__ void gemm_core(
    const short* __restrict__ Ab, int lda,
    const short* __restrict__ Bb, int ldb,
    void* __restrict__ Cb, int ldc,
    const float* __restrict__ bias, int K, float scale,
    int m0, int n0)
{
    constexpr int ACH  = WM / 2;        // 8KB A-chunks per K-tile
    constexpr int ABY  = WM * 4096;     // A region bytes per buffer
    constexpr int BUFB = ABY + 32768;   // buffer stride
    __shared__ alignas(16) char smem[2][BUFB];
    char* lds = &smem[0][0];

    const int t    = threadIdx.x;      // 0..511
    const int lane = t & 63;
    const int wave = t >> 6;
    const int wr   = wave >> 2;        // 0..1  (M half)
    const int wc   = wave & 3;         // 0..3  (N quarter)
    const int lr   = lane & 15;
    const int lq   = lane >> 4;

    // staging source: physical LDS slot (c*8192 + t*16) holds logical byte
    // L = P ^ ((P>>7 & 7)<<4); row/col pattern is chunk-invariant.
    const int srow = t >> 3;                                     // 0..63
    const int scol = (((t & 7) * 16) ^ (((t >> 3) & 7) << 4)) >> 1;
    const short* pa = Ab + (size_t)(m0 + srow) * lda + scol;
    const short* pb = Bb + (size_t)(n0 + srow) * ldb + scol;
    const size_t rsa = (size_t)64 * lda;
    const size_t rsb = (size_t)64 * ldb;
    const int ldst = t * 16;

    // swizzled read offsets
    const int roA0 = (wr * (WM * 16) + lr) * 128;
    const int roB0 = ABY + (wc * 64 + lr) * 128;
    const int cp0  = (lq << 4) ^ ((lane & 7) << 4);   // kk=0; kk=1 is cp0^64

    floatx4 acc[WM][4];
    #pragma unroll
    for (int m = 0; m < WM; ++m)
        #pragma unroll
        for (int n = 0; n < 4; ++n) acc[m][n] = (floatx4)(0.f);

    auto stA = [&](int dstb) {
        #pragma unroll
        for (int c = 0; c < ACH; ++c)
            async16(pa + (size_t)c * rsa, lds + dstb + c * 8192 + ldst);
        pa += 64;
    };
    auto stB01 = [&](int dstb) {
        async16(pb,       lds + dstb + ABY +        ldst);
        async16(pb + rsb, lds + dstb + ABY + 8192 + ldst);
    };
    auto stB23 = [&](int dstb) {
        async16(pb + 2 * rsb, lds + dstb + ABY + 16384 + ldst);
        async16(pb + 3 * rsb, lds + dstb + ABY + 24576 + ldst);
        pb += 64;
    };

    const int NT = K >> 6;   // even (16 or 32)

    // prologue: tile0 (A+B) -> buf0, tile1 A -> buf1
    stA(0); stB01(0); stB23(0); stA(BUFB);
    if constexpr (WM == 8) WAITVM(4); else WAITVM(2);
    BAR();

    for (int tt = 0; tt < NT; tt += 2) {
        #pragma unroll
        for (int half = 0; half < 2; ++half) {
            const int bufb = half ? BUFB : 0;
            const int tc   = tt + half;
            const char* rb = lds + bufb;

            if constexpr (WM == 8) {
                bf16x8 af[8], bq_[4];
                // ---- P0: kk0, n={0,1}; stage B(t+1) c0,c1 -> other
                #pragma unroll
                for (int m = 0; m < 8; ++m)
                    af[m] = *(const bf16x8*)(rb + roA0 + m * 2048 + cp0);
                bq_[0] = *(const bf16x8*)(rb + roB0 +        cp0);
                bq_[1] = *(const bf16x8*)(rb + roB0 + 2048 + cp0);
                if (tc + 1 < NT) stB01(bufb ^ BUFB);
                BAR(); MEMFENCE;
                PRIO(1);
                #pragma unroll
                for (int m = 0; m < 8; ++m) {
                    acc[m][0] = __builtin_amdgcn_mfma_f32_16x16x32_bf16(af[m], bq_[0], acc[m][0], 0, 0, 0);
                    acc[m][1] = __builtin_amdgcn_mfma_f32_16x16x32_bf16(af[m], bq_[1], acc[m][1], 0, 0, 0);
                }
                PRIO(0);
                MEMFENCE; BAR();
                // ---- P1: kk0, n={2,3}; stage B(t+1) c2,c3 -> other
                bq_[2] = *(const bf16x8*)(rb + roB0 + 2 * 2048 + cp0);
                bq_[3] = *(const bf16x8*)(rb + roB0 + 3 * 2048 + cp0);
                if (tc + 1 < NT) stB23(bufb ^ BUFB);
                BAR(); MEMFENCE;
                PRIO(1);
                #pragma unroll
                for (int m = 0; m < 8; ++m) {
                    acc[m][2] = __builtin_amdgcn_mfma_f32_16x16x32_bf16(af[m], bq_[2], acc[m][2], 0, 0, 0);
                    acc[m][3] = __builtin_amdgcn_mfma_f32_16x16x32_bf16(af[m], bq_[3], acc[m][3], 0, 0, 0);
                }
                PRIO(0);
                MEMFENCE; BAR();
                // ---- P2: kk1, n={0,1}
                #pragma unroll
                for (int m = 0; m < 8; ++m)
                    af[m] = *(const bf16x8*)(rb + roA0 + m * 2048 + (cp0 ^ 64));
                bq_[0] = *(const bf16x8*)(rb + roB0 +        (cp0 ^ 64));
                bq_[1] = *(const bf16x8*)(rb + roB0 + 2048 + (cp0 ^ 64));
                BAR(); MEMFENCE;
                PRIO(1);
                #pragma unroll
                for (int m = 0; m < 8; ++m) {
                    acc[m][0] = __builtin_amdgcn_mfma_f32_16x16x32_bf16(af[m], bq_[0], acc[m][0], 0, 0, 0);
                    acc[m][1] = __builtin_amdgcn_mfma_f32_16x16x32_bf16(af[m], bq_[1], acc[m][1], 0, 0, 0);
                }
                PRIO(0);
                MEMFENCE; BAR();
                // ---- P3: kk1, n={2,3}; stage A(t+2) -> current (A-reads
                // of this buffer were certified by P2's closing barrier)
                bq_[2] = *(const bf16x8*)(rb + roB0 + 2 * 2048 + (cp0 ^ 64));
                bq_[3] = *(const bf16x8*)(rb + roB0 + 3 * 2048 + (cp0 ^ 64));
                if (tc + 2 < NT) stA(bufb);
                BAR(); MEMFENCE;
                PRIO(1);
                #pragma unroll
                for (int m = 0; m < 8; ++m) {
                    acc[m][2] = __builtin_amdgcn_mfma_f32_16x16x32_bf16(af[m], bq_[2], acc[m][2], 0, 0, 0);
                    acc[m][3] = __builtin_amdgcn_mfma_f32_16x16x32_bf16(af[m], bq_[3], acc[m][3], 0, 0, 0);
                }
                PRIO(0);
                MEMFENCE;
                if (tc + 2 < NT)      { WAITVM(4); }
                else if (tc + 1 < NT) { WAITVM(0); }
                BAR();
            } else {
                bf16x8 af[4][2], bq_[2][2];
                // ---- P0: n={0,1}, both kk; stage B(t+1) all -> other
                #pragma unroll
                for (int m = 0; m < 4; ++m) {
                    af[m][0] = *(const bf16x8*)(rb + roA0 + m * 2048 + cp0);
                    af[m][1] = *(const bf16x8*)(rb + roA0 + m * 2048 + (cp0 ^ 64));
                }
                #pragma unroll
                for (int n = 0; n < 2; ++n) {
                    bq_[n][0] = *(const bf16x8*)(rb + roB0 + n * 2048 + cp0);
                    bq_[n][1] = *(const bf16x8*)(rb + roB0 + n * 2048 + (cp0 ^ 64));
                }
                if (tc + 1 < NT) { stB01(bufb ^ BUFB); stB23(bufb ^ BUFB); }
                BAR(); MEMFENCE;
                PRIO(1);
                #pragma unroll
                for (int m = 0; m < 4; ++m)
                    #pragma unroll
                    for (int n = 0; n < 2; ++n) {
                        acc[m][n] = __builtin_amdgcn_mfma_f32_16x16x32_bf16(af[m][0], bq_[n][0], acc[m][n], 0, 0, 0);
                        acc[m][n] = __builtin_amdgcn_mfma_f32_16x16x32_bf16(af[m][1], bq_[n][1], acc[m][n], 0, 0, 0);
                    }
                PRIO(0);
                MEMFENCE; BAR();
                // ---- P1: n={2,3}; stage A(t+2) -> current (A-reads of this
                // buffer all happened in P0, certified by its barrier)
                #pragma unroll
                for (int n = 0; n < 2; ++n) {
                    bq_[n][0] = *(const bf16x8*)(rb + roB0 + (n + 2) * 2048 + cp0);
                    bq_[n][1] = *(const bf16x8*)(rb + roB0 + (n + 2) * 2048 + (cp0 ^ 64));
                }
                if (tc + 2 < NT) stA(bufb);
                BAR(); MEMFENCE;
                PRIO(1);
                #pragma unroll
                for (int m = 0; m < 4; ++m)
                    #pragma unroll
                    for (int n = 0; n < 2; ++n) {
                        acc[m][n + 2] = __builtin_amdgcn_mfma_f32_16x16x32_bf16(af[m][0], bq_[n][0], acc[m][n + 2], 0, 0, 0);
                        acc[m][n + 2] = __builtin_amdgcn_mfma_f32_16x16x32_bf16(af[m][1], bq_[n][1], acc[m][n + 2], 0, 0, 0);
                    }
                PRIO(0);
                MEMFENCE;
                if (tc + 2 < NT)      { WAITVM(2); }
                else if (tc + 1 < NT) { WAITVM(0); }
                BAR();
            }
        }
    }

    // ---- epilogue. D layout: col = lane&15, row = (lane>>4)*4 + r ---------
    #pragma unroll
    for (int n = 0; n < 4; ++n) {
        const int gn = n0 + wc * 64 + n * 16 + lr;
        const float bv = bias ? bias[gn] : 0.f;
        #pragma unroll
        for (int m = 0; m < WM; ++m) {
            #pragma unroll
            for (int r = 0; r < 4; ++r) {
                const int gm = m0 + wr * (WM * 16) + m * 16 + lq * 4 + r;
                const float v = acc[m][n][r] * scale + bv;
                if (OUT_BF16) ((short*)Cb)[(size_t)gm * ldc + gn] = f2bf(v);
                else          ((float*)Cb)[(size_t)gm * ldc + gn] = v;
            }
        }
    }
}

// ---------------------------------------------------------------------------
// Projections: WM=4 (128x256). 768 blocks = 3 mats x 64 m-tiles x 4 n-tiles,
// XCD-swizzled (each XCD owns 8 contiguous m-tiles per matrix).
// ---------------------------------------------------------------------------
__global__ __launch_bounds__(512, 2)
void proj_qkv(const short* __restrict__ xq, const short* __restrict__ xk,
              const short* __restrict__ xv,
              const short* __restrict__ Wq_, const short* __restrict__ Wk_,
              const short* __restrict__ Wv_,
              const float* __restrict__ bq_, const float* __restrict__ bk_,
              const float* __restrict__ bv_,
              short* __restrict__ q, short* __restrict__ k, short* __restrict__ vp)
{
    const int b   = blockIdx.x;
    const int xcd = b & 7;
    const int i   = b >> 3;          // 0..95
    const int z   = i >> 5;          // 0..2 (q,k,v)
    const int r   = i & 31;
    const int mm  = r >> 2;          // 0..7
    const int nn  = r & 3;           // 0..3
    const short* X = (z == 0) ? xq : (z == 1) ? xk : xv;
    const short* W = (z == 0) ? Wq_ : (z == 1) ? Wk_ : Wv_;
    const float* bb = (z == 0) ? bq_ : (z == 1) ? bk_ : bv_;
    short* O = (z == 0) ? q : (z == 1) ? k : vp;
    gemm_core<true, 4>(X, DIMN, W, DIMN, (void*)O, DIMN, bb, DIMN, 1.f,
                       (xcd * 8 + mm) * 128, nn * 256);
}

// scores: WM=8 (256x256). 256 blocks = exactly one scheduling round.
__global__ __launch_bounds__(512, 2)
void gemm_scores(const short* __restrict__ q, const short* __restrict__ k,
                 short* __restrict__ S, float scale)
{
    const int b   = blockIdx.x;
    const int xcd = b & 7;
    const int i   = b >> 3;          // 0..31
    const int bz  = xcd >> 1;
    const int mh  = xcd & 1;
    const int mm  = i >> 3;          // 0..3
    const int nn  = i & 7;           // 0..7
    gemm_core<true, 8>(q + (size_t)bz * SEQ * DIMN, DIMN,
                       k + (size_t)bz * SEQ * DIMN, DIMN,
                       (void*)(S + (size_t)bz * SEQ * SEQ), SEQ,
                       nullptr, DIMN, scale,
                       (mh * 4 + mm) * 256, nn * 256);
}

// PV: WM=4 (128x256), K = 2048. 256 blocks = one round.
__global__ __launch_bounds__(512, 2)
void gemm_pv(const short* __restrict__ P, const short* __restrict__ vt,
             float* __restrict__ O)
{
    const int b   = blockIdx.x;
    const int xcd = b & 7;
    const int i   = b >> 3;          // 0..31
    const int bz  = xcd >> 1;
    const int mh  = xcd & 1;
    const int mm  = i >> 2;          // 0..7
    const int nn  = i & 3;           // 0..3
    gemm_core<false, 4>(P  + (size_t)bz * SEQ * SEQ,  SEQ,
                        vt + (size_t)bz * DIMN * SEQ, SEQ,
                        (void*)(O + (size_t)bz * SEQ * DIMN), DIMN,
                        nullptr, SEQ, 1.f,
                        (mh * 8 + mm) * 128, nn * 256);
}

// ---------------------------------------------------------------------------
// fp32 -> bf16 bulk convert, up to 3 arrays per launch (blockIdx.z picks).
// ---------------------------------------------------------------------------
__global__ __launch_bounds__(256)
void cvt_tri(const float* __restrict__ in0, short* __restrict__ out0,
             const float* __restrict__ in1, short* __restrict__ out1,
             const float* __restrict__ in2, short* __restrict__ out2, int n8)
{
    const int z = blockIdx.z;
    const float* in = (z == 0) ? in0 : (z == 1) ? in1 : in2;
    short* out      = (z == 0) ? out0 : (z == 1) ? out1 : out2;
    const int i = blockIdx.x * 256 + threadIdx.x;
    if (i >= n8) return;
    const float4 a0 = ((const float4*)in)[(size_t)i * 2];
    const float4 a1 = ((const float4*)in)[(size_t)i * 2 + 1];
    const float v[8] = {a0.x, a0.y, a0.z, a0.w, a1.x, a1.y, a1.z, a1.w};
    bf16x8 o;
    #pragma unroll
    for (int j = 0; j < 8; ++j) o[j] = f2bf(v[j]);
    *(bf16x8*)(out + (size_t)i * 8) = o;
}

// ---------------------------------------------------------------------------
// Effective biases: out[n] = b[n] + dot(ctx, W[n,:]) (ctx only for q,k).
// ---------------------------------------------------------------------------
__global__ __launch_bounds__(256)
void bias3(const float* __restrict__ Wq, const float* __restrict__ Wk,
           const float* __restrict__ Wv,
           const float* __restrict__ bq, const float* __restrict__ bk,
           const float* __restrict__ bv,
           const float* __restrict__ ctx,
           float* __restrict__ oq, float* __restrict__ ok, float* __restrict__ ov)
{
    const int z = blockIdx.y;
    const float* W = (z == 0) ? Wq : (z == 1) ? Wk : Wv;
    const float* b = (z == 0) ? bq : (z == 1) ? bk : bv;
    float*       o = (z == 0) ? oq : (z == 1) ? ok : ov;
    const int n    = blockIdx.x * 4 + (threadIdx.x >> 6);
    const int lane = threadIdx.x & 63;
    float s = 0.f;
    if (z < 2) {
        const float* row = W + (size_t)n * DIMN;
        for (int k = lane * 4; k < DIMN; k += 256) {
            const float4 x = *(const float4*)(row + k);
            const float4 c = *(const float4*)(ctx + k);
            s += x.x * c.x + x.y * c.y + x.z * c.z + x.w * c.w;
        }
        #pragma unroll
        for (int off = 32; off > 0; off >>= 1) s += __shfl_xor(s, off);
    }
    if (lane == 0) o[n] = b[n] + s;
}

// ---------------------------------------------------------------------------
// bf16 transpose: in [B][S][D] -> out [B][D][S], 64x64 LDS tiles.
// ---------------------------------------------------------------------------
__global__ __launch_bounds__(256)
void transpose_v(const short* __restrict__ in, short* __restrict__ out)
{
    __shared__ short t[64][68];
    const int b  = blockIdx.z;
    const int d0 = blockIdx.x * 64;
    const int s0 = blockIdx.y * 64;
    const int r  = threadIdx.x >> 3;
    const int c  = (threadIdx.x & 7) * 8;
    #pragma unroll
    for (int h = 0; h < 2; ++h) {
        const int s = r + h * 32;
        bf16x8 v = *(const bf16x8*)(in + ((size_t)b * SEQ + s0 + s) * DIMN + d0 + c);
        #pragma unroll
        for (int j = 0; j < 8; ++j) t[c + j][s] = v[j];
    }
    __syncthreads();
    #pragma unroll
    for (int h = 0; h < 2; ++h) {
        const int d = r + h * 32;
        bf16x8 v;
        #pragma unroll
        for (int j = 0; j < 8; ++j) v[j] = t[d][c + j];
        *(bf16x8*)(out + ((size_t)b * DIMN + d0 + d) * SEQ + s0 + c) = v;
    }
}

// ---------------------------------------------------------------------------
// Row softmax, in place on bf16 [M1 rows][SEQ]. XCD-aligned with scores'
// writer (batch bz lives on XCDs {2bz, 2bz+1}) so reads hit that L2.
// ---------------------------------------------------------------------------
__global__ __launch_bounds__(256)
void softmax_kernel(short* __restrict__ P)
{
    const int bid = blockIdx.x;
    const int xcd = bid & 7;
    const int i   = bid >> 3;            // 0..1023
    const int row = (xcd >> 1) * SEQ + (xcd & 1) * 1024 + i;
    short* p = P + (size_t)row * SEQ;
    const int t    = threadIdx.x;
    const int lane = t & 63;
    const int wave = t >> 6;
    __shared__ float red[8];

    bf16x8 raw = *(const bf16x8*)(p + t * 8);
    float v[8];
    float mx = -1e30f;
    #pragma unroll
    for (int j = 0; j < 8; ++j) { v[j] = bf2f(raw[j]); mx = fmaxf(mx, v[j]); }
    #pragma unroll
    for (int off = 32; off > 0; off >>= 1) mx = fmaxf(mx, __shfl_xor(mx, off));
    if (lane == 0) red[wave] = mx;
    __syncthreads();
    mx = fmaxf(fmaxf(red[0], red[1]), fmaxf(red[2], red[3]));

    float e[8], s = 0.f;
    #pragma unroll
    for (int j = 0; j < 8; ++j) { e[j] = __expf(v[j] - mx); s += e[j]; }
    #pragma unroll
    for (int off = 32; off > 0; off >>= 1) s += __shfl_xor(s, off);
    if (lane == 0) red[4 + wave] = s;
    __syncthreads();
    s = red[4] + red[5] + red[6] + red[7];
    const float inv = 1.f / s;

    bf16x8 o;
    #pragma unroll
    for (int j = 0; j < 8; ++j) o[j] = f2bf(e[j] * inv);
    *(bf16x8*)(p + t * 8) = o;
}

// ---------------------------------------------------------------------------
extern "C" void kernel_launch(void* const* d_in, const int* in_sizes, int n_in,
                              void* d_out, int out_size, void* d_ws, size_t ws_size,
                              hipStream_t stream)
{
    const float* query = (const float*)d_in[0];
    const float* key_  = (const float*)d_in[1];
    const float* value = (const float*)d_in[2];
    const float* ctx   = (const float*)d_in[3];
    const float* Wq    = (const float*)d_in[4];
    const float* bq    = (const float*)d_in[5];
    const float* Wk    = (const float*)d_in[6];
    const float* bk    = (const float*)d_in[7];
    const float* Wv    = (const float*)d_in[8];
    const float* bv    = (const float*)d_in[9];

    // Workspace (80 MB) + d_out (32 MB) doubling as scratch for xv/vp:
    //   ws:  xq [0,16) xk [16,32)  -> dead after proj -> S_b [0,32)
    //        q_b [32,48) k_b [48,64)
    //        W3 [64,70) + biases    -> dead after proj -> v_t [64,80)
    //   d_out: xv [0,16) vp [16,32) -> dead after transpose -> final output
    char* ws = (char*)d_ws;
    char* od = (char*)d_out;
    const size_t MB = 1ull << 20;
    short* xq   = (short*)(ws);
    short* xk   = (short*)(ws + 16 * MB);
    short* q_b  = (short*)(ws + 32 * MB);
    short* k_b  = (short*)(ws + 48 * MB);
    short* Wq_b = (short*)(ws + 64 * MB);
    short* Wk_b = (short*)(ws + 66 * MB);
    short* Wv_b = (short*)(ws + 68 * MB);
    float* bq_e = (float*)(ws + 70 * MB);
    float* bk_e = (float*)(ws + 70 * MB + 4096);
    float* bv_e = (float*)(ws + 70 * MB + 8192);
    short* S_b  = (short*)(ws);
    short* v_t  = (short*)(ws + 64 * MB);
    short* xv   = (short*)(od);
    short* vp   = (short*)(od + 16 * MB);

    dim3 blk(256);
    dim3 blk512(512);
    const int W8 = DIMN * DIMN / 8;  // 131072
    const int X8 = M1 * DIMN / 8;    // 1048576

    cvt_tri<<<dim3(W8 / 256, 1, 3), blk, 0, stream>>>(Wq, Wq_b, Wk, Wk_b, Wv, Wv_b, W8);
    bias3<<<dim3(DIMN / 4, 3), blk, 0, stream>>>(Wq, Wk, Wv, bq, bk, bv, ctx,
                                                 bq_e, bk_e, bv_e);
    cvt_tri<<<dim3(X8 / 256, 1, 3), blk, 0, stream>>>(query, xq, key_, xk, value, xv, X8);

    proj_qkv<<<dim3(768), blk512, 0, stream>>>(xq, xk, xv, Wq_b, Wk_b, Wv_b,
                                               bq_e, bk_e, bv_e, q_b, k_b, vp);
    transpose_v<<<dim3(DIMN / 64, SEQ / 64, BATCH), blk, 0, stream>>>(vp, v_t);

    const float scale = 1.0f / 32.0f; // DIMN^-0.5
    gemm_scores<<<dim3(256), blk512, 0, stream>>>(q_b, k_b, S_b, scale);

    softmax_kernel<<<dim3(M1), blk, 0, stream>>>(S_b);

    gemm_pv<<<dim3(256), blk512, 0, stream>>>(S_b, v_t, (float*)d_out);
}